// Round 6
// baseline (185.237 us; speedup 1.0000x reference)
//
#include <hip/hip_runtime.h>

typedef _Float16 f16x8 __attribute__((ext_vector_type(8)));
typedef _Float16 f16x4 __attribute__((ext_vector_type(4)));
typedef float f32x4 __attribute__((ext_vector_type(4)));

#define MFMA32(a, b, c) __builtin_amdgcn_mfma_f32_16x16x32_f16(a, b, c, 0, 0, 0)
#define MFMA16(a, b, c) __builtin_amdgcn_mfma_f32_16x16x16f16(a, b, c, 0, 0, 0)

// ---------------------------------------------------------------- converts
__global__ __launch_bounds__(256) void f32_to_f16_kernel(
    const float* __restrict__ in, _Float16* __restrict__ out, int n) {
  int i = (blockIdx.x * 256 + threadIdx.x) * 4;
  if (i >= n) return;
  float4 v = *(const float4*)(in + i);
  f16x4 h;
  h.x = (_Float16)v.x; h.y = (_Float16)v.y; h.z = (_Float16)v.z; h.w = (_Float16)v.w;
  *(f16x4*)(out + i) = h;
}

__global__ __launch_bounds__(256) void w_to_f16_kernel(
    const float* __restrict__ w0, const float* __restrict__ w1,
    const float* __restrict__ w2, const float* __restrict__ w3,
    _Float16* __restrict__ o0, _Float16* __restrict__ o1,
    _Float16* __restrict__ o2, _Float16* __restrict__ o3) {
  int z = blockIdx.y;
  const float* in = (z == 0) ? w0 : (z == 1) ? w1 : (z == 2) ? w2 : w3;
  _Float16* out = (z == 0) ? o0 : (z == 1) ? o1 : (z == 2) ? o2 : o3;
  int i = (blockIdx.x * 256 + threadIdx.x) * 4;
  float4 v = *(const float4*)(in + i);
  f16x4 h;
  h.x = (_Float16)v.x; h.y = (_Float16)v.y; h.z = (_Float16)v.z; h.w = (_Float16)v.w;
  *(f16x4*)(out + i) = h;
}

// ---------------------------------------------------------------- GEMM core
__device__ __forceinline__ void gld_lds16(_Float16* l, const _Float16* g) {
  __builtin_amdgcn_global_load_lds(
      (const __attribute__((address_space(1))) unsigned int*)g,
      (__attribute__((address_space(3))) unsigned int*)l, 16, 0, 0);
}

__device__ __forceinline__ void stage_async(_Float16* lds, const _Float16* g,
                                            int ldg, int wid, int lane) {
#pragma unroll
  for (int j = 0; j < 4; ++j) {
    int blk = wid * 4 + j;                 // 16 blocks of 8 rows x 64 halves
    int row = blk * 8 + (lane >> 3);
    int col = (lane & 7) * 8;
    gld_lds16(lds + blk * 512, g + (size_t)row * ldg + col);  // uniform LDS base
  }
}

__device__ __forceinline__ void gemm_core(const _Float16* __restrict__ A,
                                          const _Float16* __restrict__ W,
                                          _Float16* As, _Float16* Bs,
                                          f32x4 acc[4][4], int m0, int n0, int tid) {
  int lane = tid & 63, wid = tid >> 6;
  int lr = lane & 15, lg = lane >> 4;
  int wm = (wid >> 1) * 64, wn = (wid & 1) * 64;
  for (int k0 = 0; k0 < 1024; k0 += 64) {
    __syncthreads();
    stage_async(As, A + (size_t)m0 * 1024 + k0, 1024, wid, lane);
    stage_async(Bs, W + (size_t)n0 * 1024 + k0, 1024, wid, lane);
    __syncthreads();
#pragma unroll
    for (int ks = 0; ks < 2; ++ks) {
      f16x8 af[4], bfv[4];
#pragma unroll
      for (int mf = 0; mf < 4; ++mf)
        af[mf] = *(const f16x8*)(As + (wm + mf * 16 + lr) * 64 + ks * 32 + lg * 8);
#pragma unroll
      for (int nf = 0; nf < 4; ++nf)
        bfv[nf] = *(const f16x8*)(Bs + (wn + nf * 16 + lr) * 64 + ks * 32 + lg * 8);
#pragma unroll
      for (int mf = 0; mf < 4; ++mf)
#pragma unroll
        for (int nf = 0; nf < 4; ++nf)
          acc[mf][nf] = MFMA32(af[mf], bfv[nf], acc[mf][nf]);
    }
  }
}

// --------------------------------------------------- QKV projection GEMM
// z=0: Q; z=1: K (both [B,H,S,64]); z=2: V transposed [B,H,64,S] via LDS
// transpose so the global stores are coalesced 16B (was a 2B scatter).
#define TRP 136  // Tr stride (halves): 272B -> 2-way bank aliasing, 16B-aligned

__global__ __launch_bounds__(256) void proj_gemm(
    const _Float16* __restrict__ xb,
    const _Float16* __restrict__ wq, const _Float16* __restrict__ wk,
    const _Float16* __restrict__ wv,
    const float* __restrict__ bq, const float* __restrict__ bk,
    const float* __restrict__ bv,
    _Float16* __restrict__ qo, _Float16* __restrict__ ko, _Float16* __restrict__ vo) {
  __shared__ __align__(16) _Float16 As[128 * 64];
  __shared__ __align__(16) _Float16 Bs[128 * 64];
  __shared__ __align__(16) _Float16 Tr[64 * TRP];
  int z = blockIdx.z;
  const _Float16* W = (z == 0) ? wq : ((z == 1) ? wk : wv);
  const float* bias = (z == 0) ? bq : ((z == 1) ? bk : bv);
  int tid = threadIdx.x;
  int m0 = blockIdx.y * 128, n0 = blockIdx.x * 128;
  f32x4 acc[4][4] = {};
  gemm_core(xb, W, As, Bs, acc, m0, n0, tid);

  int lane = tid & 63, wid = tid >> 6;
  int lr = lane & 15, lg = lane >> 4;
  int wm = (wid >> 1) * 64, wn = (wid & 1) * 64;

  if (z == 2) {
    // ---- transpose epilogue: VT[col][s], coalesced stores
    int b = m0 >> 11, s0 = m0 & 2047;
#pragma unroll
    for (int half = 0; half < 2; ++half) {
      if ((wid & 1) == half) {             // waves owning cols [half*64, half*64+64)
#pragma unroll
        for (int nf = 0; nf < 4; ++nf) {
          int c = nf * 16 + lr;            // local col 0..63
          float bb = bias[n0 + half * 64 + c];
#pragma unroll
          for (int mf = 0; mf < 4; ++mf)
#pragma unroll
            for (int i = 0; i < 4; ++i)
              Tr[c * TRP + wm + mf * 16 + lg * 4 + i] = (_Float16)(acc[mf][nf][i] + bb);
        }
      }
      __syncthreads();
      int h = (n0 >> 6) + half;
#pragma unroll
      for (int j = 0; j < 4; ++j) {        // 1024 chunks of 8 halves
        int cid = tid + 256 * j;
        int c = cid >> 4, seg = cid & 15;
        f16x8 v = *(const f16x8*)(Tr + c * TRP + seg * 8);
        *(f16x8*)(vo + ((size_t)(b * 16 + h) * 64 + c) * 2048 + s0 + seg * 8) = v;
      }
      __syncthreads();
    }
  } else {
    _Float16* o = (z == 0) ? qo : ko;
#pragma unroll
    for (int nf = 0; nf < 4; ++nf) {
      int col = n0 + wn + nf * 16 + lr;
      float bb = bias[col];
      int h = col >> 6, hd = col & 63;
#pragma unroll
      for (int mf = 0; mf < 4; ++mf)
#pragma unroll
        for (int i = 0; i < 4; ++i) {
          int row = m0 + wm + mf * 16 + lg * 4 + i;
          int b = row >> 11, s = row & 2047;
          o[((size_t)(b * 16 + h) * 2048 + s) * 64 + hd] = (_Float16)(acc[mf][nf][i] + bb);
        }
    }
  }
}

// --------------------------------------------------------- output GEMM (f32)
__global__ __launch_bounds__(256) void out_gemm(
    const _Float16* __restrict__ attn, const _Float16* __restrict__ wo,
    const float* __restrict__ bo, float* __restrict__ out) {
  __shared__ __align__(16) _Float16 As[128 * 64];
  __shared__ __align__(16) _Float16 Bs[128 * 64];
  int tid = threadIdx.x;
  int m0 = blockIdx.y * 128, n0 = blockIdx.x * 128;
  f32x4 acc[4][4] = {};
  gemm_core(attn, wo, As, Bs, acc, m0, n0, tid);

  int lane = tid & 63;
  int lr = lane & 15, lg = lane >> 4;
  int wm = ((tid >> 6) >> 1) * 64, wn = ((tid >> 6) & 1) * 64;
#pragma unroll
  for (int nf = 0; nf < 4; ++nf) {
    int col = n0 + wn + nf * 16 + lr;
    float bb = bo[col];
#pragma unroll
    for (int mf = 0; mf < 4; ++mf)
#pragma unroll
      for (int i = 0; i < 4; ++i) {
        int row = m0 + wm + mf * 16 + lg * 4 + i;
        out[(size_t)row * 1024 + col] = acc[mf][nf][i] + bb;
      }
  }
}

// --------------------------------------------------------- flash attention v6
// 2 waves x 32 q = QBLK 64, grid (32,16,2) = 1024 blocks = 4/CU (4 streams).
// qt = b ? 31-x : x  -> co-resident blocks carry complementary work.
// K/V double-buffered; tile t+1 loaded to regs BEFORE computing tile t
// (latency hidden under compute); ONE barrier per tile.
// Per-tile math identical to round-5 (passed): always-rescale, full mask.
#define LDP 72  // padded LDS stride (halves)

__device__ __forceinline__ void load_tile(const _Float16* __restrict__ Kh,
                                          const _Float16* __restrict__ VTh,
                                          int kv0, int tid, int4 rk[4], int4 rv[4]) {
#pragma unroll
  for (int j = 0; j < 4; ++j) {
    int cid = tid + 128 * j, r = cid >> 3, c = (cid & 7) * 8;
    rk[j] = *(const int4*)(Kh + (size_t)(kv0 + r) * 64 + c);
    rv[j] = *(const int4*)(VTh + (size_t)r * 2048 + kv0 + c);
  }
}

__device__ __forceinline__ void write_tile(_Float16* Ksb, _Float16* Vsb,
                                           int tid, const int4 rk[4], const int4 rv[4]) {
#pragma unroll
  for (int j = 0; j < 4; ++j) {
    int cid = tid + 128 * j, r = cid >> 3, c = (cid & 7) * 8;
    *(int4*)(Ksb + r * LDP + c) = rk[j];
    *(int4*)(Vsb + r * LDP + c) = rv[j];
  }
}

template <bool MASK>
__device__ __forceinline__ void attn_tile32(const _Float16* Ks, const _Float16* Vs,
                                            const f16x8 qb[2][2], int kv0, int qwb,
                                            int lr, int lg,
                                            float m[2], float l[2], f32x4 ot[2][4]) {
  const float L2E = 1.44269504f;
  const float NINF = -__builtin_inff();
  f16x8 kf0[4], kf1[4];
#pragma unroll
  for (int nf = 0; nf < 4; ++nf) {
    kf0[nf] = *(const f16x8*)(Ks + (nf * 16 + lr) * LDP + lg * 8);
    kf1[nf] = *(const f16x8*)(Ks + (nf * 16 + lr) * LDP + 32 + lg * 8);
  }
  f32x4 sc[2][4];
  __builtin_amdgcn_s_setprio(1);
#pragma unroll
  for (int h = 0; h < 2; ++h)
#pragma unroll
    for (int nf = 0; nf < 4; ++nf) {
      f32x4 z = {0.f, 0.f, 0.f, 0.f};
      z = MFMA32(kf0[nf], qb[h][0], z);
      z = MFMA32(kf1[nf], qb[h][1], z);
      sc[h][nf] = z;
    }
  __builtin_amdgcn_s_setprio(0);
  if (MASK) {
#pragma unroll
    for (int h = 0; h < 2; ++h) {
      int qg = qwb + h * 16 + lr;
#pragma unroll
      for (int nf = 0; nf < 4; ++nf)
#pragma unroll
        for (int i = 0; i < 4; ++i) {
          int kg = kv0 + nf * 16 + lg * 4 + i;
          sc[h][nf][i] = (kg <= qg) ? sc[h][nf][i] : NINF;
        }
    }
  }
  f16x4 pf[2][4];
#pragma unroll
  for (int h = 0; h < 2; ++h) {
    f32x4 mx4 = sc[h][0];
#pragma unroll
    for (int nf = 1; nf < 4; ++nf)
#pragma unroll
      for (int i = 0; i < 4; ++i) mx4[i] = fmaxf(mx4[i], sc[h][nf][i]);
    float tm = fmaxf(fmaxf(mx4[0], mx4[1]), fmaxf(mx4[2], mx4[3]));
    tm = fmaxf(tm, __shfl_xor(tm, 16));
    tm = fmaxf(tm, __shfl_xor(tm, 32));
    float mn = fmaxf(m[h], tm);
    float alpha = __builtin_amdgcn_exp2f((m[h] - mn) * L2E);
    m[h] = mn;
    float mnL = mn * L2E;
    float ps = 0.f;
#pragma unroll
    for (int nf = 0; nf < 4; ++nf)
#pragma unroll
      for (int i = 0; i < 4; ++i) {
        float p = __builtin_amdgcn_exp2f(sc[h][nf][i] * L2E - mnL);
        ps += p;
        pf[h][nf][i] = (_Float16)p;
      }
    ps += __shfl_xor(ps, 16);
    ps += __shfl_xor(ps, 32);
    l[h] = l[h] * alpha + ps;
#pragma unroll
    for (int dt = 0; dt < 4; ++dt)
#pragma unroll
      for (int i = 0; i < 4; ++i) ot[h][dt][i] *= alpha;
  }
  __builtin_amdgcn_s_setprio(1);
#pragma unroll
  for (int nf = 0; nf < 4; ++nf)
#pragma unroll
    for (int dt = 0; dt < 4; ++dt) {
      f16x4 vf = *(const f16x4*)(Vs + (dt * 16 + lr) * LDP + nf * 16 + lg * 4);
      ot[0][dt] = MFMA16(vf, pf[0][nf], ot[0][dt]);
      ot[1][dt] = MFMA16(vf, pf[1][nf], ot[1][dt]);
    }
  __builtin_amdgcn_s_setprio(0);
}

__global__ __launch_bounds__(128, 2) void attn_kernel(
    const _Float16* __restrict__ Q, const _Float16* __restrict__ K,
    const _Float16* __restrict__ VT, _Float16* __restrict__ O) {
  __shared__ __align__(16) _Float16 Ks[2][64 * LDP];
  __shared__ __align__(16) _Float16 Vs[2][64 * LDP];
  int tid = threadIdx.x, lane = tid & 63, wid = tid >> 6;
  int qt = blockIdx.z ? (31 - (int)blockIdx.x) : (int)blockIdx.x;
  int hh = blockIdx.y, b = blockIdx.z;
  size_t hoff = (size_t)(b * 16 + hh) * 2048 * 64;
  const _Float16* Qh = Q + hoff;
  const _Float16* Kh = K + hoff;
  const _Float16* VTh = VT + hoff;
  int qwb = qt * 64 + wid * 32;        // wave q base (32 rows)
  int lr = lane & 15, lg = lane >> 4;

  f16x8 qb[2][2];
#pragma unroll
  for (int h = 0; h < 2; ++h) {
    const _Float16* qp = Qh + (size_t)(qwb + h * 16 + lr) * 64;
    qb[h][0] = *(const f16x8*)(qp + lg * 8);
    qb[h][1] = *(const f16x8*)(qp + 32 + lg * 8);
#pragma unroll
    for (int j = 0; j < 8; ++j) {      // fold 1/sqrt(64) into Q (exact: 2^-3)
      qb[h][0][j] *= (_Float16)0.125f;
      qb[h][1][j] *= (_Float16)0.125f;
    }
  }

  float m[2] = {-__builtin_inff(), -__builtin_inff()};
  float l[2] = {0.f, 0.f};
  f32x4 ot[2][4] = {};

  int4 rk[4], rv[4];
  load_tile(Kh, VTh, 0, tid, rk, rv);
  write_tile(&Ks[0][0], &Vs[0][0], tid, rk, rv);
  __syncthreads();

  for (int t = 0; t <= qt; ++t) {      // kv tiles 0..qt (both waves: aw == qt)
    int cur = t & 1;
    if (t < qt) load_tile(Kh, VTh, (t + 1) * 64, tid, rk, rv);
    if (t < qt)
      attn_tile32<false>(&Ks[cur][0], &Vs[cur][0], qb, t * 64, qwb, lr, lg, m, l, ot);
    else
      attn_tile32<true>(&Ks[cur][0], &Vs[cur][0], qb, t * 64, qwb, lr, lg, m, l, ot);
    if (t < qt) {
      write_tile(&Ks[cur ^ 1][0], &Vs[cur ^ 1][0], tid, rk, rv);
      __syncthreads();
    }
  }

#pragma unroll
  for (int h = 0; h < 2; ++h) {
    float inv = 1.f / l[h];
    _Float16* Oh = O + ((size_t)b * 2048 + qwb + h * 16 + lr) * 1024 + hh * 64;
#pragma unroll
    for (int dt = 0; dt < 4; ++dt) {
      f16x4 o;
#pragma unroll
      for (int i = 0; i < 4; ++i) o[i] = (_Float16)(ot[h][dt][i] * inv);
      *(f16x4*)(Oh + dt * 16 + lg * 4) = o;
    }
  }
}

// ------------------------------------------------------------------- launch
extern "C" void kernel_launch(void* const* d_in, const int* in_sizes, int n_in,
                              void* d_out, int out_size, void* d_ws, size_t ws_size,
                              hipStream_t stream) {
  const float* x  = (const float*)d_in[0];
  const float* Wq = (const float*)d_in[1];
  const float* bq = (const float*)d_in[2];
  const float* Wk = (const float*)d_in[3];
  const float* bk = (const float*)d_in[4];
  const float* Wv = (const float*)d_in[5];
  const float* bv = (const float*)d_in[6];
  const float* Wo = (const float*)d_in[7];
  const float* bo = (const float*)d_in[8];
  float* out = (float*)d_out;

  _Float16* ws  = (_Float16*)d_ws;
  _Float16* xb  = ws;                 // 4194304
  _Float16* wqb = ws + 4194304;
  _Float16* wkb = ws + 5242880;
  _Float16* wvb = ws + 6291456;
  _Float16* wob = ws + 7340032;
  _Float16* qw  = ws + 8388608;       // [B,H,S,64]
  _Float16* kw  = ws + 12582912;      // [B,H,S,64]
  _Float16* vtw = ws + 16777216;      // [B,H,64,S]
  _Float16* aw  = ws + 20971520;      // [B,S,1024]

  f32_to_f16_kernel<<<4096, 256, 0, stream>>>(x, xb, 4194304);
  w_to_f16_kernel<<<dim3(1024, 4), 256, 0, stream>>>(Wq, Wk, Wv, Wo,
                                                     wqb, wkb, wvb, wob);

  proj_gemm<<<dim3(8, 32, 3), 256, 0, stream>>>(xb, wqb, wkb, wvb, bq, bk, bv,
                                                qw, kw, vtw);
  attn_kernel<<<dim3(32, 16, 2), 128, 0, stream>>>(qw, kw, vtw, aw);
  out_gemm<<<dim3(8, 32, 1), 256, 0, stream>>>(aw, wob, bo, out);
}

// Round 7
// 144.875 us; speedup vs baseline: 1.2786x; 1.2786x over previous
//
#include <hip/hip_runtime.h>

typedef _Float16 f16x8 __attribute__((ext_vector_type(8)));
typedef _Float16 f16x4 __attribute__((ext_vector_type(4)));
typedef float f32x4 __attribute__((ext_vector_type(4)));

#define MFMA32(a, b, c) __builtin_amdgcn_mfma_f32_16x16x32_f16(a, b, c, 0, 0, 0)
#define MFMA16(a, b, c) __builtin_amdgcn_mfma_f32_16x16x16f16(a, b, c, 0, 0, 0)

// ---------------------------------------------------------------- converts
__global__ __launch_bounds__(256) void f32_to_f16_kernel(
    const float* __restrict__ in, _Float16* __restrict__ out, int n) {
  int i = (blockIdx.x * 256 + threadIdx.x) * 4;
  if (i >= n) return;
  float4 v = *(const float4*)(in + i);
  f16x4 h;
  h.x = (_Float16)v.x; h.y = (_Float16)v.y; h.z = (_Float16)v.z; h.w = (_Float16)v.w;
  *(f16x4*)(out + i) = h;
}

__global__ __launch_bounds__(256) void w_to_f16_kernel(
    const float* __restrict__ w0, const float* __restrict__ w1,
    const float* __restrict__ w2, const float* __restrict__ w3,
    _Float16* __restrict__ o0, _Float16* __restrict__ o1,
    _Float16* __restrict__ o2, _Float16* __restrict__ o3) {
  int z = blockIdx.y;
  const float* in = (z == 0) ? w0 : (z == 1) ? w1 : (z == 2) ? w2 : w3;
  _Float16* out = (z == 0) ? o0 : (z == 1) ? o1 : (z == 2) ? o2 : o3;
  int i = (blockIdx.x * 256 + threadIdx.x) * 4;
  float4 v = *(const float4*)(in + i);
  f16x4 h;
  h.x = (_Float16)v.x; h.y = (_Float16)v.y; h.z = (_Float16)v.z; h.w = (_Float16)v.w;
  *(f16x4*)(out + i) = h;
}

// ---------------------------------------------------------------- GEMM core
__device__ __forceinline__ void gld_lds16(_Float16* l, const _Float16* g) {
  __builtin_amdgcn_global_load_lds(
      (const __attribute__((address_space(1))) unsigned int*)g,
      (__attribute__((address_space(3))) unsigned int*)l, 16, 0, 0);
}

__device__ __forceinline__ void stage_async(_Float16* lds, const _Float16* g,
                                            int ldg, int wid, int lane) {
#pragma unroll
  for (int j = 0; j < 4; ++j) {
    int blk = wid * 4 + j;                 // 16 blocks of 8 rows x 64 halves
    int row = blk * 8 + (lane >> 3);
    int col = (lane & 7) * 8;
    gld_lds16(lds + blk * 512, g + (size_t)row * ldg + col);  // uniform LDS base
  }
}

__device__ __forceinline__ void gemm_core(const _Float16* __restrict__ A,
                                          const _Float16* __restrict__ W,
                                          _Float16* As, _Float16* Bs,
                                          f32x4 acc[4][4], int m0, int n0, int tid) {
  int lane = tid & 63, wid = tid >> 6;
  int lr = lane & 15, lg = lane >> 4;
  int wm = (wid >> 1) * 64, wn = (wid & 1) * 64;
  for (int k0 = 0; k0 < 1024; k0 += 64) {
    __syncthreads();
    stage_async(As, A + (size_t)m0 * 1024 + k0, 1024, wid, lane);
    stage_async(Bs, W + (size_t)n0 * 1024 + k0, 1024, wid, lane);
    __syncthreads();
#pragma unroll
    for (int ks = 0; ks < 2; ++ks) {
      f16x8 af[4], bfv[4];
#pragma unroll
      for (int mf = 0; mf < 4; ++mf)
        af[mf] = *(const f16x8*)(As + (wm + mf * 16 + lr) * 64 + ks * 32 + lg * 8);
#pragma unroll
      for (int nf = 0; nf < 4; ++nf)
        bfv[nf] = *(const f16x8*)(Bs + (wn + nf * 16 + lr) * 64 + ks * 32 + lg * 8);
#pragma unroll
      for (int mf = 0; mf < 4; ++mf)
#pragma unroll
        for (int nf = 0; nf < 4; ++nf)
          acc[mf][nf] = MFMA32(af[mf], bfv[nf], acc[mf][nf]);
    }
  }
}

// --------------------------------------------------- QKV projection GEMM
// z=0: Q; z=1: K (both [B,H,S,64]); z=2: V transposed [B,H,64,S] via LDS
// transpose so the global stores are coalesced 16B.
#define TRP 136

__global__ __launch_bounds__(256) void proj_gemm(
    const _Float16* __restrict__ xb,
    const _Float16* __restrict__ wq, const _Float16* __restrict__ wk,
    const _Float16* __restrict__ wv,
    const float* __restrict__ bq, const float* __restrict__ bk,
    const float* __restrict__ bv,
    _Float16* __restrict__ qo, _Float16* __restrict__ ko, _Float16* __restrict__ vo) {
  __shared__ __align__(16) _Float16 As[128 * 64];
  __shared__ __align__(16) _Float16 Bs[128 * 64];
  __shared__ __align__(16) _Float16 Tr[64 * TRP];
  int z = blockIdx.z;
  const _Float16* W = (z == 0) ? wq : ((z == 1) ? wk : wv);
  const float* bias = (z == 0) ? bq : ((z == 1) ? bk : bv);
  int tid = threadIdx.x;
  int m0 = blockIdx.y * 128, n0 = blockIdx.x * 128;
  f32x4 acc[4][4] = {};
  gemm_core(xb, W, As, Bs, acc, m0, n0, tid);

  int lane = tid & 63, wid = tid >> 6;
  int lr = lane & 15, lg = lane >> 4;
  int wm = (wid >> 1) * 64, wn = (wid & 1) * 64;

  if (z == 2) {
    int b = m0 >> 11, s0 = m0 & 2047;
#pragma unroll
    for (int half = 0; half < 2; ++half) {
      if ((wid & 1) == half) {
#pragma unroll
        for (int nf = 0; nf < 4; ++nf) {
          int c = nf * 16 + lr;
          float bb = bias[n0 + half * 64 + c];
#pragma unroll
          for (int mf = 0; mf < 4; ++mf)
#pragma unroll
            for (int i = 0; i < 4; ++i)
              Tr[c * TRP + wm + mf * 16 + lg * 4 + i] = (_Float16)(acc[mf][nf][i] + bb);
        }
      }
      __syncthreads();
      int h = (n0 >> 6) + half;
#pragma unroll
      for (int j = 0; j < 4; ++j) {
        int cid = tid + 256 * j;
        int c = cid >> 4, seg = cid & 15;
        f16x8 v = *(const f16x8*)(Tr + c * TRP + seg * 8);
        *(f16x8*)(vo + ((size_t)(b * 16 + h) * 64 + c) * 2048 + s0 + seg * 8) = v;
      }
      __syncthreads();
    }
  } else {
    _Float16* o = (z == 0) ? qo : ko;
#pragma unroll
    for (int nf = 0; nf < 4; ++nf) {
      int col = n0 + wn + nf * 16 + lr;
      float bb = bias[col];
      int h = col >> 6, hd = col & 63;
#pragma unroll
      for (int mf = 0; mf < 4; ++mf)
#pragma unroll
        for (int i = 0; i < 4; ++i) {
          int row = m0 + wm + mf * 16 + lg * 4 + i;
          int b = row >> 11, s = row & 2047;
          o[((size_t)(b * 16 + h) * 2048 + s) * 64 + hd] = (_Float16)(acc[mf][nf][i] + bb);
        }
    }
  }
}

// --------------------------------------------------------- output GEMM (f32)
__global__ __launch_bounds__(256) void out_gemm(
    const _Float16* __restrict__ attn, const _Float16* __restrict__ wo,
    const float* __restrict__ bo, float* __restrict__ out) {
  __shared__ __align__(16) _Float16 As[128 * 64];
  __shared__ __align__(16) _Float16 Bs[128 * 64];
  int tid = threadIdx.x;
  int m0 = blockIdx.y * 128, n0 = blockIdx.x * 128;
  f32x4 acc[4][4] = {};
  gemm_core(attn, wo, As, Bs, acc, m0, n0, tid);

  int lane = tid & 63;
  int lr = lane & 15, lg = lane >> 4;
  int wm = ((tid >> 6) >> 1) * 64, wn = ((tid >> 6) & 1) * 64;
#pragma unroll
  for (int nf = 0; nf < 4; ++nf) {
    int col = n0 + wn + nf * 16 + lr;
    float bb = bo[col];
#pragma unroll
    for (int mf = 0; mf < 4; ++mf)
#pragma unroll
      for (int i = 0; i < 4; ++i) {
        int row = m0 + wm + mf * 16 + lg * 4 + i;
        out[(size_t)row * 1024 + col] = acc[mf][nf][i] + bb;
      }
  }
}

// --------------------------------------------------------- flash attention v7
// r5 structure (4 waves x 32 q = QBLK 128, grid (16,16,2), single-buffer LDS,
// per-tile math verbatim) + complementary qt pairing (co-resident blocks
// (x,y,0)/(x,y,1) together always carry 34 tile-units) + issue-early K/V
// loads in NAMED int4 regs (no arrays -> no scratch) + setprio on MFMA.
#define LDP 72  // padded LDS stride (halves)

template <bool MASK>
__device__ __forceinline__ void attn_tile32(const _Float16* Ks, const _Float16* Vs,
                                            const f16x8 qb[2][2], int kv0, int qwb,
                                            int lr, int lg,
                                            float m[2], float l[2], f32x4 ot[2][4]) {
  const float L2E = 1.44269504f;
  const float NINF = -__builtin_inff();
  f16x8 kf0[4], kf1[4];
#pragma unroll
  for (int nf = 0; nf < 4; ++nf) {
    kf0[nf] = *(const f16x8*)(Ks + (nf * 16 + lr) * LDP + lg * 8);
    kf1[nf] = *(const f16x8*)(Ks + (nf * 16 + lr) * LDP + 32 + lg * 8);
  }
  f32x4 sc[2][4];
  __builtin_amdgcn_s_setprio(1);
#pragma unroll
  for (int h = 0; h < 2; ++h)
#pragma unroll
    for (int nf = 0; nf < 4; ++nf) {
      f32x4 z = {0.f, 0.f, 0.f, 0.f};
      z = MFMA32(kf0[nf], qb[h][0], z);
      z = MFMA32(kf1[nf], qb[h][1], z);
      sc[h][nf] = z;
    }
  __builtin_amdgcn_s_setprio(0);
  if (MASK) {
#pragma unroll
    for (int h = 0; h < 2; ++h) {
      int qg = qwb + h * 16 + lr;
#pragma unroll
      for (int nf = 0; nf < 4; ++nf)
#pragma unroll
        for (int i = 0; i < 4; ++i) {
          int kg = kv0 + nf * 16 + lg * 4 + i;
          sc[h][nf][i] = (kg <= qg) ? sc[h][nf][i] : NINF;
        }
    }
  }
  f16x4 pf[2][4];
#pragma unroll
  for (int h = 0; h < 2; ++h) {
    f32x4 mx4 = sc[h][0];
#pragma unroll
    for (int nf = 1; nf < 4; ++nf)
#pragma unroll
      for (int i = 0; i < 4; ++i) mx4[i] = fmaxf(mx4[i], sc[h][nf][i]);
    float tm = fmaxf(fmaxf(mx4[0], mx4[1]), fmaxf(mx4[2], mx4[3]));
    tm = fmaxf(tm, __shfl_xor(tm, 16));
    tm = fmaxf(tm, __shfl_xor(tm, 32));
    float mn = fmaxf(m[h], tm);
    float alpha = __builtin_amdgcn_exp2f((m[h] - mn) * L2E);
    m[h] = mn;
    float mnL = mn * L2E;
    float ps = 0.f;
#pragma unroll
    for (int nf = 0; nf < 4; ++nf)
#pragma unroll
      for (int i = 0; i < 4; ++i) {
        float p = __builtin_amdgcn_exp2f(sc[h][nf][i] * L2E - mnL);
        ps += p;
        pf[h][nf][i] = (_Float16)p;
      }
    ps += __shfl_xor(ps, 16);
    ps += __shfl_xor(ps, 32);
    l[h] = l[h] * alpha + ps;
#pragma unroll
    for (int dt = 0; dt < 4; ++dt)
#pragma unroll
      for (int i = 0; i < 4; ++i) ot[h][dt][i] *= alpha;
  }
  __builtin_amdgcn_s_setprio(1);
#pragma unroll
  for (int nf = 0; nf < 4; ++nf)
#pragma unroll
    for (int dt = 0; dt < 4; ++dt) {
      f16x4 vf = *(const f16x4*)(Vs + (dt * 16 + lr) * LDP + nf * 16 + lg * 4);
      ot[0][dt] = MFMA16(vf, pf[0][nf], ot[0][dt]);
      ot[1][dt] = MFMA16(vf, pf[1][nf], ot[1][dt]);
    }
  __builtin_amdgcn_s_setprio(0);
}

__global__ __launch_bounds__(256) void attn_kernel(
    const _Float16* __restrict__ Q, const _Float16* __restrict__ K,
    const _Float16* __restrict__ VT, _Float16* __restrict__ O) {
  __shared__ __align__(16) _Float16 Ks[64 * LDP];
  __shared__ __align__(16) _Float16 Vs[64 * LDP];
  int tid = threadIdx.x, lane = tid & 63, wid = tid >> 6;
  // complementary pairing: co-resident (x,y,0)/(x,y,1) -> qt x and 15-x
  int qt = blockIdx.z ? (15 - (int)blockIdx.x) : (int)blockIdx.x;
  int hh = blockIdx.y, b = blockIdx.z;
  size_t hoff = (size_t)(b * 16 + hh) * 2048 * 64;
  const _Float16* Qh = Q + hoff;
  const _Float16* Kh = K + hoff;
  const _Float16* VTh = VT + hoff;
  int qwb = qt * 128 + wid * 32;
  int lr = lane & 15, lg = lane >> 4;

  f16x8 qb[2][2];
#pragma unroll
  for (int h = 0; h < 2; ++h) {
    const _Float16* qp = Qh + (size_t)(qwb + h * 16 + lr) * 64;
    qb[h][0] = *(const f16x8*)(qp + lg * 8);
    qb[h][1] = *(const f16x8*)(qp + 32 + lg * 8);
#pragma unroll
    for (int j = 0; j < 8; ++j) {
      qb[h][0][j] *= (_Float16)0.125f;
      qb[h][1][j] *= (_Float16)0.125f;
    }
  }

  float m[2] = {-__builtin_inff(), -__builtin_inff()};
  float l[2] = {0.f, 0.f};
  f32x4 ot[2][4] = {};

  // staging geometry: 256 threads, two int4 chunks per array
  int r0 = tid >> 3, c0 = (tid & 7) * 8;   // chunk rows 0..31
  int r1 = r0 + 32;                        // chunk rows 32..63
  // NAMED registers (no arrays -> no scratch)
  int4 rk0 = *(const int4*)(Kh + (size_t)r0 * 64 + c0);
  int4 rk1 = *(const int4*)(Kh + (size_t)r1 * 64 + c0);
  int4 rv0 = *(const int4*)(VTh + (size_t)r0 * 2048 + c0);
  int4 rv1 = *(const int4*)(VTh + (size_t)r1 * 2048 + c0);

  int aw = qwb >> 6;                 // first masked tile for this wave
  int ntiles = 2 * qt + 2;
  for (int t = 0; t < ntiles; ++t) {
    __syncthreads();                 // previous tile's LDS reads complete
    *(int4*)(Ks + r0 * LDP + c0) = rk0;
    *(int4*)(Ks + r1 * LDP + c0) = rk1;
    *(int4*)(Vs + r0 * LDP + c0) = rv0;
    *(int4*)(Vs + r1 * LDP + c0) = rv1;
    if (t + 1 < ntiles) {            // issue next tile's loads; land during compute
      int nkv = (t + 1) * 64;
      rk0 = *(const int4*)(Kh + (size_t)(nkv + r0) * 64 + c0);
      rk1 = *(const int4*)(Kh + (size_t)(nkv + r1) * 64 + c0);
      rv0 = *(const int4*)(VTh + (size_t)r0 * 2048 + nkv + c0);
      rv1 = *(const int4*)(VTh + (size_t)r1 * 2048 + nkv + c0);
    }
    __syncthreads();                 // staging visible
    if (t < aw)
      attn_tile32<false>(Ks, Vs, qb, t * 64, qwb, lr, lg, m, l, ot);
    else
      attn_tile32<true>(Ks, Vs, qb, t * 64, qwb, lr, lg, m, l, ot);
  }

#pragma unroll
  for (int h = 0; h < 2; ++h) {
    float inv = 1.f / l[h];
    _Float16* Oh = O + ((size_t)b * 2048 + qwb + h * 16 + lr) * 1024 + hh * 64;
#pragma unroll
    for (int dt = 0; dt < 4; ++dt) {
      f16x4 o;
#pragma unroll
      for (int i = 0; i < 4; ++i) o[i] = (_Float16)(ot[h][dt][i] * inv);
      *(f16x4*)(Oh + dt * 16 + lg * 4) = o;
    }
  }
}

// ------------------------------------------------------------------- launch
extern "C" void kernel_launch(void* const* d_in, const int* in_sizes, int n_in,
                              void* d_out, int out_size, void* d_ws, size_t ws_size,
                              hipStream_t stream) {
  const float* x  = (const float*)d_in[0];
  const float* Wq = (const float*)d_in[1];
  const float* bq = (const float*)d_in[2];
  const float* Wk = (const float*)d_in[3];
  const float* bk = (const float*)d_in[4];
  const float* Wv = (const float*)d_in[5];
  const float* bv = (const float*)d_in[6];
  const float* Wo = (const float*)d_in[7];
  const float* bo = (const float*)d_in[8];
  float* out = (float*)d_out;

  _Float16* ws  = (_Float16*)d_ws;
  _Float16* xb  = ws;
  _Float16* wqb = ws + 4194304;
  _Float16* wkb = ws + 5242880;
  _Float16* wvb = ws + 6291456;
  _Float16* wob = ws + 7340032;
  _Float16* qw  = ws + 8388608;       // [B,H,S,64]
  _Float16* kw  = ws + 12582912;      // [B,H,S,64]
  _Float16* vtw = ws + 16777216;      // [B,H,64,S]
  _Float16* aw  = ws + 20971520;      // [B,S,1024]

  f32_to_f16_kernel<<<4096, 256, 0, stream>>>(x, xb, 4194304);
  w_to_f16_kernel<<<dim3(1024, 4), 256, 0, stream>>>(Wq, Wk, Wv, Wo,
                                                     wqb, wkb, wvb, wob);

  proj_gemm<<<dim3(8, 32, 3), 256, 0, stream>>>(xb, wqb, wkb, wvb, bq, bk, bv,
                                                qw, kw, vtw);
  attn_kernel<<<dim3(16, 16, 2), 256, 0, stream>>>(qw, kw, vtw, aw);
  out_gemm<<<dim3(8, 32, 1), 256, 0, stream>>>(aw, wob, bo, out);
}

// Round 8
// 136.691 us; speedup vs baseline: 1.3551x; 1.0599x over previous
//
#include <hip/hip_runtime.h>

typedef _Float16 f16x8 __attribute__((ext_vector_type(8)));
typedef _Float16 f16x4 __attribute__((ext_vector_type(4)));
typedef float f32x4 __attribute__((ext_vector_type(4)));

#define MFMA32(a, b, c) __builtin_amdgcn_mfma_f32_16x16x32_f16(a, b, c, 0, 0, 0)
#define MFMA16(a, b, c) __builtin_amdgcn_mfma_f32_16x16x16f16(a, b, c, 0, 0, 0)

// ---------------------------------------------------------------- converts
// one launch: x (1048576 chunks) + 4 weights (262144 chunks each), 4 f32/chunk
__global__ __launch_bounds__(256) void convert_all(
    const float* __restrict__ x,
    const float* __restrict__ w0, const float* __restrict__ w1,
    const float* __restrict__ w2, const float* __restrict__ w3,
    _Float16* __restrict__ xb,
    _Float16* __restrict__ o0, _Float16* __restrict__ o1,
    _Float16* __restrict__ o2, _Float16* __restrict__ o3) {
  int chunk = blockIdx.x * 256 + threadIdx.x;
  const float* in;
  _Float16* out;
  int i;
  if (chunk < 1048576) {
    in = x; out = xb; i = chunk * 4;
  } else {
    int t = chunk - 1048576;
    int z = t >> 18;
    i = (t & 262143) * 4;
    in = (z == 0) ? w0 : (z == 1) ? w1 : (z == 2) ? w2 : w3;
    out = (z == 0) ? o0 : (z == 1) ? o1 : (z == 2) ? o2 : o3;
  }
  float4 v = *(const float4*)(in + i);
  f16x4 h;
  h.x = (_Float16)v.x; h.y = (_Float16)v.y; h.z = (_Float16)v.z; h.w = (_Float16)v.w;
  *(f16x4*)(out + i) = h;
}

// ---------------------------------------------------------------- GEMM core
__device__ __forceinline__ void gld_lds16(_Float16* l, const _Float16* g) {
  __builtin_amdgcn_global_load_lds(
      (const __attribute__((address_space(1))) unsigned int*)g,
      (__attribute__((address_space(3))) unsigned int*)l, 16, 0, 0);
}

__device__ __forceinline__ void stage_async(_Float16* lds, const _Float16* g,
                                            int ldg, int wid, int lane) {
#pragma unroll
  for (int j = 0; j < 4; ++j) {
    int blk = wid * 4 + j;                 // 16 blocks of 8 rows x 64 halves
    int row = blk * 8 + (lane >> 3);
    int col = (lane & 7) * 8;
    gld_lds16(lds + blk * 512, g + (size_t)row * ldg + col);  // uniform LDS base
  }
}

__device__ __forceinline__ void gemm_core(const _Float16* __restrict__ A,
                                          const _Float16* __restrict__ W,
                                          _Float16* As, _Float16* Bs,
                                          f32x4 acc[4][4], int m0, int n0, int tid) {
  int lane = tid & 63, wid = tid >> 6;
  int lr = lane & 15, lg = lane >> 4;
  int wm = (wid >> 1) * 64, wn = (wid & 1) * 64;
  for (int k0 = 0; k0 < 1024; k0 += 64) {
    __syncthreads();
    stage_async(As, A + (size_t)m0 * 1024 + k0, 1024, wid, lane);
    stage_async(Bs, W + (size_t)n0 * 1024 + k0, 1024, wid, lane);
    __syncthreads();
#pragma unroll
    for (int ks = 0; ks < 2; ++ks) {
      f16x8 af[4], bfv[4];
#pragma unroll
      for (int mf = 0; mf < 4; ++mf)
        af[mf] = *(const f16x8*)(As + (wm + mf * 16 + lr) * 64 + ks * 32 + lg * 8);
#pragma unroll
      for (int nf = 0; nf < 4; ++nf)
        bfv[nf] = *(const f16x8*)(Bs + (wn + nf * 16 + lr) * 64 + ks * 32 + lg * 8);
#pragma unroll
      for (int mf = 0; mf < 4; ++mf)
#pragma unroll
        for (int nf = 0; nf < 4; ++nf)
          acc[mf][nf] = MFMA32(af[mf], bfv[nf], acc[mf][nf]);
    }
  }
}

// --------------------------------------------------- QKV projection GEMM
// grid (32, 8, 3): x = m-block, y = n-block -> linear id = x + 32y + 256z,
// XCD = x%8: all n-blocks (and all z) of an A-panel share one XCD's L2.
// z=0: Q; z=1: K ([B,H,S,64]); z=2: V transposed [B,H,64,S] via LDS transpose
// REUSING As/Bs as the buffer (LDS stays 32 KB -> higher occupancy).
#define TRP 136

__global__ __launch_bounds__(256) void proj_gemm(
    const _Float16* __restrict__ xb,
    const _Float16* __restrict__ wq, const _Float16* __restrict__ wk,
    const _Float16* __restrict__ wv,
    const float* __restrict__ bq, const float* __restrict__ bk,
    const float* __restrict__ bv,
    _Float16* __restrict__ qo, _Float16* __restrict__ ko, _Float16* __restrict__ vo) {
  __shared__ __align__(16) _Float16 smem[2 * 128 * 64];
  _Float16* As = smem;
  _Float16* Bs = smem + 8192;
  int z = blockIdx.z;
  const _Float16* W = (z == 0) ? wq : ((z == 1) ? wk : wv);
  const float* bias = (z == 0) ? bq : ((z == 1) ? bk : bv);
  int tid = threadIdx.x;
  int m0 = blockIdx.x * 128, n0 = blockIdx.y * 128;
  f32x4 acc[4][4] = {};
  gemm_core(xb, W, As, Bs, acc, m0, n0, tid);

  int lane = tid & 63, wid = tid >> 6;
  int lr = lane & 15, lg = lane >> 4;
  int wm = (wid >> 1) * 64, wn = (wid & 1) * 64;

  if (z == 2) {
    _Float16* Tr = smem;                   // reuse As+Bs (needs 64*TRP <= 16384)
    int b = m0 >> 11, s0 = m0 & 2047;
    __syncthreads();                       // all waves done reading As/Bs
#pragma unroll
    for (int half = 0; half < 2; ++half) {
      if ((wid & 1) == half) {
#pragma unroll
        for (int nf = 0; nf < 4; ++nf) {
          int c = nf * 16 + lr;
          float bb = bias[n0 + half * 64 + c];
#pragma unroll
          for (int mf = 0; mf < 4; ++mf)
#pragma unroll
            for (int i = 0; i < 4; ++i)
              Tr[c * TRP + wm + mf * 16 + lg * 4 + i] = (_Float16)(acc[mf][nf][i] + bb);
        }
      }
      __syncthreads();
      int h = (n0 >> 6) + half;
#pragma unroll
      for (int j = 0; j < 4; ++j) {
        int cid = tid + 256 * j;
        int c = cid >> 4, seg = cid & 15;
        f16x8 v = *(const f16x8*)(Tr + c * TRP + seg * 8);
        *(f16x8*)(vo + ((size_t)(b * 16 + h) * 64 + c) * 2048 + s0 + seg * 8) = v;
      }
      __syncthreads();
    }
  } else {
    _Float16* o = (z == 0) ? qo : ko;
#pragma unroll
    for (int nf = 0; nf < 4; ++nf) {
      int col = n0 + wn + nf * 16 + lr;
      float bb = bias[col];
      int h = col >> 6, hd = col & 63;
#pragma unroll
      for (int mf = 0; mf < 4; ++mf)
#pragma unroll
        for (int i = 0; i < 4; ++i) {
          int row = m0 + wm + mf * 16 + lg * 4 + i;
          int b = row >> 11, s = row & 2047;
          o[((size_t)(b * 16 + h) * 2048 + s) * 64 + hd] = (_Float16)(acc[mf][nf][i] + bb);
        }
    }
  }
}

// --------------------------------------------------------- output GEMM (f32)
// grid (32, 8): x = m-block -> XCD = x%8, A-panel L2-local.
__global__ __launch_bounds__(256) void out_gemm(
    const _Float16* __restrict__ attn, const _Float16* __restrict__ wo,
    const float* __restrict__ bo, float* __restrict__ out) {
  __shared__ __align__(16) _Float16 As[128 * 64];
  __shared__ __align__(16) _Float16 Bs[128 * 64];
  int tid = threadIdx.x;
  int m0 = blockIdx.x * 128, n0 = blockIdx.y * 128;
  f32x4 acc[4][4] = {};
  gemm_core(attn, wo, As, Bs, acc, m0, n0, tid);

  int lane = tid & 63;
  int lr = lane & 15, lg = lane >> 4;
  int wm = ((tid >> 6) >> 1) * 64, wn = ((tid >> 6) & 1) * 64;
#pragma unroll
  for (int nf = 0; nf < 4; ++nf) {
    int col = n0 + wn + nf * 16 + lr;
    float bb = bo[col];
#pragma unroll
    for (int mf = 0; mf < 4; ++mf)
#pragma unroll
      for (int i = 0; i < 4; ++i) {
        int row = m0 + wm + mf * 16 + lg * 4 + i;
        out[(size_t)row * 1024 + col] = acc[mf][nf][i] + bb;
      }
  }
}

// --------------------------------------------------------- flash attention v7
// (unchanged from round 7 — passed, 4 waves x 32 q = QBLK 128, grid (16,16,2),
// complementary qt pairing, issue-early K/V loads in named int4 regs.)
#define LDP 72  // padded LDS stride (halves)

template <bool MASK>
__device__ __forceinline__ void attn_tile32(const _Float16* Ks, const _Float16* Vs,
                                            const f16x8 qb[2][2], int kv0, int qwb,
                                            int lr, int lg,
                                            float m[2], float l[2], f32x4 ot[2][4]) {
  const float L2E = 1.44269504f;
  const float NINF = -__builtin_inff();
  f16x8 kf0[4], kf1[4];
#pragma unroll
  for (int nf = 0; nf < 4; ++nf) {
    kf0[nf] = *(const f16x8*)(Ks + (nf * 16 + lr) * LDP + lg * 8);
    kf1[nf] = *(const f16x8*)(Ks + (nf * 16 + lr) * LDP + 32 + lg * 8);
  }
  f32x4 sc[2][4];
  __builtin_amdgcn_s_setprio(1);
#pragma unroll
  for (int h = 0; h < 2; ++h)
#pragma unroll
    for (int nf = 0; nf < 4; ++nf) {
      f32x4 z = {0.f, 0.f, 0.f, 0.f};
      z = MFMA32(kf0[nf], qb[h][0], z);
      z = MFMA32(kf1[nf], qb[h][1], z);
      sc[h][nf] = z;
    }
  __builtin_amdgcn_s_setprio(0);
  if (MASK) {
#pragma unroll
    for (int h = 0; h < 2; ++h) {
      int qg = qwb + h * 16 + lr;
#pragma unroll
      for (int nf = 0; nf < 4; ++nf)
#pragma unroll
        for (int i = 0; i < 4; ++i) {
          int kg = kv0 + nf * 16 + lg * 4 + i;
          sc[h][nf][i] = (kg <= qg) ? sc[h][nf][i] : NINF;
        }
    }
  }
  f16x4 pf[2][4];
#pragma unroll
  for (int h = 0; h < 2; ++h) {
    f32x4 mx4 = sc[h][0];
#pragma unroll
    for (int nf = 1; nf < 4; ++nf)
#pragma unroll
      for (int i = 0; i < 4; ++i) mx4[i] = fmaxf(mx4[i], sc[h][nf][i]);
    float tm = fmaxf(fmaxf(mx4[0], mx4[1]), fmaxf(mx4[2], mx4[3]));
    tm = fmaxf(tm, __shfl_xor(tm, 16));
    tm = fmaxf(tm, __shfl_xor(tm, 32));
    float mn = fmaxf(m[h], tm);
    float alpha = __builtin_amdgcn_exp2f((m[h] - mn) * L2E);
    m[h] = mn;
    float mnL = mn * L2E;
    float ps = 0.f;
#pragma unroll
    for (int nf = 0; nf < 4; ++nf)
#pragma unroll
      for (int i = 0; i < 4; ++i) {
        float p = __builtin_amdgcn_exp2f(sc[h][nf][i] * L2E - mnL);
        ps += p;
        pf[h][nf][i] = (_Float16)p;
      }
    ps += __shfl_xor(ps, 16);
    ps += __shfl_xor(ps, 32);
    l[h] = l[h] * alpha + ps;
#pragma unroll
    for (int dt = 0; dt < 4; ++dt)
#pragma unroll
      for (int i = 0; i < 4; ++i) ot[h][dt][i] *= alpha;
  }
  __builtin_amdgcn_s_setprio(1);
#pragma unroll
  for (int nf = 0; nf < 4; ++nf)
#pragma unroll
    for (int dt = 0; dt < 4; ++dt) {
      f16x4 vf = *(const f16x4*)(Vs + (dt * 16 + lr) * LDP + nf * 16 + lg * 4);
      ot[0][dt] = MFMA16(vf, pf[0][nf], ot[0][dt]);
      ot[1][dt] = MFMA16(vf, pf[1][nf], ot[1][dt]);
    }
  __builtin_amdgcn_s_setprio(0);
}

__global__ __launch_bounds__(256) void attn_kernel(
    const _Float16* __restrict__ Q, const _Float16* __restrict__ K,
    const _Float16* __restrict__ VT, _Float16* __restrict__ O) {
  __shared__ __align__(16) _Float16 Ks[64 * LDP];
  __shared__ __align__(16) _Float16 Vs[64 * LDP];
  int tid = threadIdx.x, lane = tid & 63, wid = tid >> 6;
  int qt = blockIdx.z ? (15 - (int)blockIdx.x) : (int)blockIdx.x;
  int hh = blockIdx.y, b = blockIdx.z;
  size_t hoff = (size_t)(b * 16 + hh) * 2048 * 64;
  const _Float16* Qh = Q + hoff;
  const _Float16* Kh = K + hoff;
  const _Float16* VTh = VT + hoff;
  int qwb = qt * 128 + wid * 32;
  int lr = lane & 15, lg = lane >> 4;

  f16x8 qb[2][2];
#pragma unroll
  for (int h = 0; h < 2; ++h) {
    const _Float16* qp = Qh + (size_t)(qwb + h * 16 + lr) * 64;
    qb[h][0] = *(const f16x8*)(qp + lg * 8);
    qb[h][1] = *(const f16x8*)(qp + 32 + lg * 8);
#pragma unroll
    for (int j = 0; j < 8; ++j) {
      qb[h][0][j] *= (_Float16)0.125f;
      qb[h][1][j] *= (_Float16)0.125f;
    }
  }

  float m[2] = {-__builtin_inff(), -__builtin_inff()};
  float l[2] = {0.f, 0.f};
  f32x4 ot[2][4] = {};

  int r0 = tid >> 3, c0 = (tid & 7) * 8;
  int r1 = r0 + 32;
  int4 rk0 = *(const int4*)(Kh + (size_t)r0 * 64 + c0);
  int4 rk1 = *(const int4*)(Kh + (size_t)r1 * 64 + c0);
  int4 rv0 = *(const int4*)(VTh + (size_t)r0 * 2048 + c0);
  int4 rv1 = *(const int4*)(VTh + (size_t)r1 * 2048 + c0);

  int aw = qwb >> 6;
  int ntiles = 2 * qt + 2;
  for (int t = 0; t < ntiles; ++t) {
    __syncthreads();
    *(int4*)(Ks + r0 * LDP + c0) = rk0;
    *(int4*)(Ks + r1 * LDP + c0) = rk1;
    *(int4*)(Vs + r0 * LDP + c0) = rv0;
    *(int4*)(Vs + r1 * LDP + c0) = rv1;
    if (t + 1 < ntiles) {
      int nkv = (t + 1) * 64;
      rk0 = *(const int4*)(Kh + (size_t)(nkv + r0) * 64 + c0);
      rk1 = *(const int4*)(Kh + (size_t)(nkv + r1) * 64 + c0);
      rv0 = *(const int4*)(VTh + (size_t)r0 * 2048 + nkv + c0);
      rv1 = *(const int4*)(VTh + (size_t)r1 * 2048 + nkv + c0);
    }
    __syncthreads();
    if (t < aw)
      attn_tile32<false>(Ks, Vs, qb, t * 64, qwb, lr, lg, m, l, ot);
    else
      attn_tile32<true>(Ks, Vs, qb, t * 64, qwb, lr, lg, m, l, ot);
  }

#pragma unroll
  for (int h = 0; h < 2; ++h) {
    float inv = 1.f / l[h];
    _Float16* Oh = O + ((size_t)b * 2048 + qwb + h * 16 + lr) * 1024 + hh * 64;
#pragma unroll
    for (int dt = 0; dt < 4; ++dt) {
      f16x4 o;
#pragma unroll
      for (int i = 0; i < 4; ++i) o[i] = (_Float16)(ot[h][dt][i] * inv);
      *(f16x4*)(Oh + dt * 16 + lg * 4) = o;
    }
  }
}

// ------------------------------------------------------------------- launch
extern "C" void kernel_launch(void* const* d_in, const int* in_sizes, int n_in,
                              void* d_out, int out_size, void* d_ws, size_t ws_size,
                              hipStream_t stream) {
  const float* x  = (const float*)d_in[0];
  const float* Wq = (const float*)d_in[1];
  const float* bq = (const float*)d_in[2];
  const float* Wk = (const float*)d_in[3];
  const float* bk = (const float*)d_in[4];
  const float* Wv = (const float*)d_in[5];
  const float* bv = (const float*)d_in[6];
  const float* Wo = (const float*)d_in[7];
  const float* bo = (const float*)d_in[8];
  float* out = (float*)d_out;

  _Float16* ws  = (_Float16*)d_ws;
  _Float16* xb  = ws;
  _Float16* wqb = ws + 4194304;
  _Float16* wkb = ws + 5242880;
  _Float16* wvb = ws + 6291456;
  _Float16* wob = ws + 7340032;
  _Float16* qw  = ws + 8388608;       // [B,H,S,64]
  _Float16* kw  = ws + 12582912;      // [B,H,S,64]
  _Float16* vtw = ws + 16777216;      // [B,H,64,S]
  _Float16* aw  = ws + 20971520;      // [B,S,1024]

  convert_all<<<8192, 256, 0, stream>>>(x, Wq, Wk, Wv, Wo,
                                        xb, wqb, wkb, wvb, wob);

  proj_gemm<<<dim3(32, 8, 3), 256, 0, stream>>>(xb, wqb, wkb, wvb, bq, bk, bv,
                                                qw, kw, vtw);
  attn_kernel<<<dim3(16, 16, 2), 256, 0, stream>>>(qw, kw, vtw, aw);
  out_gemm<<<dim3(32, 8), 256, 0, stream>>>(aw, wob, bo, out);
}